// Round 7
// baseline (195.704 us; speedup 1.0000x reference)
//
#include <hip/hip_runtime.h>
#include <hip/hip_bf16.h>
#include <cstdint>

#define N_PROT 19000
#define N_DRUGS 4200
#define BATCH 8192
#define D0 1024
#define D1 512
#define D2 128
#define NROWS (2 * BATCH)  // 16384 MLP rows, interleaved: r = 2*i + s
#define MAXNNZ 192         // Binomial(19000,0.002): mean 38, sd 6.2 — >20 sigma
#define NCHUNK 8           // gather column chunks (one per XCD)
#define CCOLS (D0 / NCHUNK)

typedef __bf16 bf16_t;
typedef __bf16 bf16x8 __attribute__((ext_vector_type(8)));
typedef __bf16 bf16x4 __attribute__((ext_vector_type(4)));
typedef __bf16 bf16x2 __attribute__((ext_vector_type(2)));
typedef float f32x4 __attribute__((ext_vector_type(4)));

// async global->LDS, 16B per lane, wave-uniform LDS base + lane*16 (HW rule)
#define GLOAD_LDS16(gsrc, ldst)                                        \
  __builtin_amdgcn_global_load_lds(                                    \
      (const __attribute__((address_space(1))) void*)(gsrc),           \
      (__attribute__((address_space(3))) void*)(ldst), 16, 0, 0)

// ---------------------------------------------------------------------------
// Kernel 1: weight conversions. W0->W0b bf16; W1->W1T bf16; W2->W2T bf16.
// ---------------------------------------------------------------------------
__global__ __launch_bounds__(256) void k_convert(
    const float* __restrict__ W0, const float* __restrict__ W1,
    const float* __restrict__ W2, bf16_t* __restrict__ W0b,
    bf16_t* __restrict__ W1T, bf16_t* __restrict__ W2T)
{
  const int S = gridDim.x * 256;
  const int tid0 = blockIdx.x * 256 + threadIdx.x;
  constexpr int NV0 = N_PROT * D0 / 4;  // 4,864,000 float4 groups

  int v = tid0;
  for (; v + 3 * S < NV0; v += 4 * S) {
    f32x4 w0 = reinterpret_cast<const f32x4*>(W0)[v];
    f32x4 w1 = reinterpret_cast<const f32x4*>(W0)[v + S];
    f32x4 w2 = reinterpret_cast<const f32x4*>(W0)[v + 2 * S];
    f32x4 w3 = reinterpret_cast<const f32x4*>(W0)[v + 3 * S];
    bf16x4 o0 = {(bf16_t)w0[0], (bf16_t)w0[1], (bf16_t)w0[2], (bf16_t)w0[3]};
    bf16x4 o1 = {(bf16_t)w1[0], (bf16_t)w1[1], (bf16_t)w1[2], (bf16_t)w1[3]};
    bf16x4 o2 = {(bf16_t)w2[0], (bf16_t)w2[1], (bf16_t)w2[2], (bf16_t)w2[3]};
    bf16x4 o3 = {(bf16_t)w3[0], (bf16_t)w3[1], (bf16_t)w3[2], (bf16_t)w3[3]};
    reinterpret_cast<bf16x4*>(W0b)[v] = o0;
    reinterpret_cast<bf16x4*>(W0b)[v + S] = o1;
    reinterpret_cast<bf16x4*>(W0b)[v + 2 * S] = o2;
    reinterpret_cast<bf16x4*>(W0b)[v + 3 * S] = o3;
  }
  for (; v < NV0; v += S) {
    f32x4 w = reinterpret_cast<const f32x4*>(W0)[v];
    bf16x4 o = {(bf16_t)w[0], (bf16_t)w[1], (bf16_t)w[2], (bf16_t)w[3]};
    reinterpret_cast<bf16x4*>(W0b)[v] = o;
  }
  for (int idx = tid0; idx < D0 * D1; idx += S) {   // idx = n*D0 + k
    const int n = idx >> 10, k = idx & (D0 - 1);
    W1T[idx] = (bf16_t)W1[(size_t)k * D1 + n];
  }
  for (int idx = tid0; idx < D1 * D2; idx += S) {   // idx = n*D1 + k
    const int n = idx >> 9, k = idx & (D1 - 1);
    W2T[idx] = (bf16_t)W2[(size_t)k * D2 + n];
  }
}

// ---------------------------------------------------------------------------
// Kernel 2: scan table rows -> per-drug nonzero index lists (round-4 form).
// ---------------------------------------------------------------------------
__global__ __launch_bounds__(256) void k_scan(
    const uint32_t* __restrict__ table_u, int* __restrict__ g_cnt,
    int* __restrict__ g_idx)
{
  __shared__ int s_idx[MAXNNZ];
  __shared__ int s_cnt;
  const int d = blockIdx.x;
  if (threadIdx.x == 0) s_cnt = 0;
  __syncthreads();

  const uint4* row = reinterpret_cast<const uint4*>(table_u + (size_t)d * N_PROT);
  constexpr int NQ = N_PROT / 4;  // 4750

#define SCAN_BODY(v, qq)                                                        \
  if ((v).x | (v).y | (v).z | (v).w) {                                          \
    if ((v).x) { int k = atomicAdd(&s_cnt, 1); if (k < MAXNNZ) s_idx[k] = 4 * (qq) + 0; } \
    if ((v).y) { int k = atomicAdd(&s_cnt, 1); if (k < MAXNNZ) s_idx[k] = 4 * (qq) + 1; } \
    if ((v).z) { int k = atomicAdd(&s_cnt, 1); if (k < MAXNNZ) s_idx[k] = 4 * (qq) + 2; } \
    if ((v).w) { int k = atomicAdd(&s_cnt, 1); if (k < MAXNNZ) s_idx[k] = 4 * (qq) + 3; } \
  }

  int q = threadIdx.x;
  for (; q + 256 < NQ; q += 512) {
    uint4 v0 = row[q];
    uint4 v1 = row[q + 256];
    SCAN_BODY(v0, q)
    SCAN_BODY(v1, q + 256)
  }
  for (; q < NQ; q += 256) {
    uint4 v = row[q];
    SCAN_BODY(v, q)
  }
#undef SCAN_BODY

  __syncthreads();
  const int n = min(s_cnt, MAXNNZ);
  if (threadIdx.x == 0) g_cnt[d] = n;
  for (int t = threadIdx.x; t < n; t += 256) g_idx[(size_t)d * MAXNNZ + t] = s_idx[t];
}

// ---------------------------------------------------------------------------
// Kernel 3: XCD-chunked gather. h0[d][:] = sum of listed W0b rows + b0.
// ---------------------------------------------------------------------------
__global__ __launch_bounds__(64) void k_gather(
    const bf16_t* __restrict__ W0b, const int* __restrict__ g_cnt,
    const int* __restrict__ g_idx, const float* __restrict__ b0,
    float* __restrict__ h0)
{
  __shared__ int s_idx[MAXNNZ];
  const int chunk = blockIdx.x & (NCHUNK - 1);
  const int d = blockIdx.x >> 3;
  const int n = g_cnt[d];
  for (int t = threadIdx.x; t < n; t += 64) s_idx[t] = g_idx[(size_t)d * MAXNNZ + t];
  __syncthreads();

  const int col = chunk * CCOLS + threadIdx.x * 2;
  float c0 = 0.f, c1 = 0.f, d0_ = 0.f, d1_ = 0.f;
  float e0 = 0.f, e1 = 0.f, f0 = 0.f, f1 = 0.f;
  int t = 0;
  for (; t + 4 <= n; t += 4) {
    bf16x2 w0 = *reinterpret_cast<const bf16x2*>(W0b + (size_t)s_idx[t] * D0 + col);
    bf16x2 w1 = *reinterpret_cast<const bf16x2*>(W0b + (size_t)s_idx[t + 1] * D0 + col);
    bf16x2 w2 = *reinterpret_cast<const bf16x2*>(W0b + (size_t)s_idx[t + 2] * D0 + col);
    bf16x2 w3 = *reinterpret_cast<const bf16x2*>(W0b + (size_t)s_idx[t + 3] * D0 + col);
    c0 += (float)w0[0]; c1 += (float)w0[1];
    d0_ += (float)w1[0]; d1_ += (float)w1[1];
    e0 += (float)w2[0]; e1 += (float)w2[1];
    f0 += (float)w3[0]; f1 += (float)w3[1];
  }
  for (; t < n; ++t) {
    bf16x2 w = *reinterpret_cast<const bf16x2*>(W0b + (size_t)s_idx[t] * D0 + col);
    c0 += (float)w[0]; c1 += (float)w[1];
  }
  float2 o;
  o.x = ((c0 + d0_) + (e0 + f0)) + b0[col];
  o.y = ((c1 + d1_) + (e1 + f1)) + b0[col + 1];
  *reinterpret_cast<float2*>(h0 + (size_t)d * D0 + col) = o;
}

// ---------------------------------------------------------------------------
// Kernel 4: H[r][:] = relu(h0[drug(r)] + c(r)*W0_last), bf16.
// (b0 already folded into h0 by k_gather.) r = 2i+s interleaved.
// ---------------------------------------------------------------------------
__global__ __launch_bounds__(256) void k_build_H(
    const float* __restrict__ h0, const int* __restrict__ pairs,
    const float* __restrict__ conc, const float* __restrict__ W0last,
    bf16_t* __restrict__ H)
{
  const int r = blockIdx.x;
  const int drug = pairs[r];                       // pairs[i][s] with r=2i+s
  const float c = conc[3 * (r >> 1) + 1 + (r & 1)];

  const int j = threadIdx.x * 4;
  float4 hv = *reinterpret_cast<const float4*>(h0 + (size_t)drug * D0 + j);
  float4 wl = *reinterpret_cast<const float4*>(W0last + j);
  bf16x4 o;
  o[0] = (bf16_t)fmaxf(hv.x + c * wl.x, 0.f);
  o[1] = (bf16_t)fmaxf(hv.y + c * wl.y, 0.f);
  o[2] = (bf16_t)fmaxf(hv.z + c * wl.z, 0.f);
  o[3] = (bf16_t)fmaxf(hv.w + c * wl.w, 0.f);
  *reinterpret_cast<bf16x4*>(H + (size_t)r * D0 + j) = o;
}

// ---------------------------------------------------------------------------
// Kernel 5: m97-style GEMM1. H1 = relu(H @ W1 + b1), A=H [M][1024] bf16,
// B=W1T [512][1024] bf16 (N-major, K-contiguous). 128x128 tile, BK=32,
// 4 waves 2x2 (each 64x64 via 4x4 16x16x32 MFMA). Staging via
// global_load_lds width=16, double-buffered linear LDS (m97: 874 TF ref).
// Schedule: one barrier per K-step; prefetch of step k+1 issued right after
// the barrier so it drains at the NEXT barrier (overlaps the 16 MFMAs).
// LDS tile layout: [128 rows][32 k] bf16 row-major (64B rows), linear.
//   gload_lds inst (wave w, issue i): LDS bytes (w*2+i)*1024..+1023 =
//   rows (w*2+i)*16 + (lane>>2), k-slot (lane&3)*8. Source matches.
// C/D: lane l, reg r -> row = 4*(l>>4)+r, col = l&15  [m89-verified]
// ---------------------------------------------------------------------------
__global__ __launch_bounds__(256) void k_gemm1(
    const bf16_t* __restrict__ A, const bf16_t* __restrict__ BT,
    const float* __restrict__ bias, bf16_t* __restrict__ C)
{
  constexpr int K = D0;       // 1024
  constexpr int N = D1;       // 512
  constexpr int NT = K / 32;  // 32 K-steps
  __shared__ bf16_t sA[2][128 * 32];  // 2 x 8 KB
  __shared__ bf16_t sB[2][128 * 32];  // 2 x 8 KB

  const int tid = threadIdx.x;
  const int w = tid >> 6;
  const int lane = tid & 63;
  const int wr = w >> 1, wc = w & 1;
  const int row0 = blockIdx.x * 128;
  const int col0 = blockIdx.y * 128;
  const int fr = lane & 15;
  const int q = lane >> 4;

  // staging coords (per-lane global source; wave-uniform LDS dest)
  const int srow0 = (w * 2 + 0) * 16 + (lane >> 2);
  const int srow1 = (w * 2 + 1) * 16 + (lane >> 2);
  const int skel = (lane & 3) * 8;
  const bf16_t* a_src0 = A + (size_t)(row0 + srow0) * K + skel;
  const bf16_t* a_src1 = A + (size_t)(row0 + srow1) * K + skel;
  const bf16_t* b_src0 = BT + (size_t)(col0 + srow0) * K + skel;
  const bf16_t* b_src1 = BT + (size_t)(col0 + srow1) * K + skel;
  const int ldst0 = (w * 2 + 0) * 512;  // element offset of the 1KB window
  const int ldst1 = (w * 2 + 1) * 512;

  auto stage = [&](int buf, int k0) {
    GLOAD_LDS16(a_src0 + k0, &sA[buf][ldst0]);
    GLOAD_LDS16(a_src1 + k0, &sA[buf][ldst1]);
    GLOAD_LDS16(b_src0 + k0, &sB[buf][ldst0]);
    GLOAD_LDS16(b_src1 + k0, &sB[buf][ldst1]);
  };

  f32x4 acc[4][4] = {};
  stage(0, 0);
  for (int ks = 0; ks < NT; ++ks) {
    const int buf = ks & 1;
    __syncthreads();  // compiler drains vmcnt(0): staged tile now visible
    if (ks + 1 < NT) stage(buf ^ 1, (ks + 1) * 32);  // in flight under MFMA

    bf16x8 a[4], b[4];
#pragma unroll
    for (int m = 0; m < 4; ++m)
      a[m] = *reinterpret_cast<const bf16x8*>(&sA[buf][(wr * 64 + m * 16 + fr) * 32 + q * 8]);
#pragma unroll
    for (int n = 0; n < 4; ++n)
      b[n] = *reinterpret_cast<const bf16x8*>(&sB[buf][(wc * 64 + n * 16 + fr) * 32 + q * 8]);
#pragma unroll
    for (int m = 0; m < 4; ++m)
#pragma unroll
      for (int n = 0; n < 4; ++n)
        acc[m][n] = __builtin_amdgcn_mfma_f32_16x16x32_bf16(a[m], b[n], acc[m][n], 0, 0, 0);
  }

  // epilogue: bias + relu -> bf16
#pragma unroll
  for (int m = 0; m < 4; ++m)
#pragma unroll
    for (int n = 0; n < 4; ++n) {
      const int col = col0 + wc * 64 + n * 16 + fr;
      const float bb = bias[col];
#pragma unroll
      for (int r = 0; r < 4; ++r) {
        const int row = row0 + wr * 64 + m * 16 + 4 * q + r;
        C[(size_t)row * N + col] = (bf16_t)fmaxf(acc[m][n][r] + bb, 0.f);
      }
    }
}

// ---------------------------------------------------------------------------
// Kernel 6: gemm2 fused with the pair-dot (round-3 version).
// Z = H1 @ W2 + b2 (128 cols), rows interleaved. Block = 128 rows x 128 cols,
// 4 waves 2x2. Pair rows 2j,2j+1 are lane-local in the accumulator.
// ---------------------------------------------------------------------------
__global__ __launch_bounds__(256) void k_gemm2_dot(
    const bf16_t* __restrict__ A, const bf16_t* __restrict__ BT,
    const float* __restrict__ bias, float* __restrict__ out)
{
  __shared__ float red[2][64];
  const int wid = threadIdx.x >> 6;
  const int lane = threadIdx.x & 63;
  const int wr = wid >> 1, wc = wid & 1;
  const int row0 = blockIdx.x * 128 + wr * 64;
  const int col0 = wc * 64;
  const int fr = lane & 15;
  const int fk = (lane >> 4) * 8;
  constexpr int K = D1;

  f32x4 acc[4][4] = {};
#pragma unroll 2
  for (int k0 = 0; k0 < K; k0 += 32) {
    bf16x8 a[4], b[4];
#pragma unroll
    for (int m = 0; m < 4; ++m)
      a[m] = *reinterpret_cast<const bf16x8*>(A + (size_t)(row0 + m * 16 + fr) * K + k0 + fk);
#pragma unroll
    for (int n = 0; n < 4; ++n)
      b[n] = *reinterpret_cast<const bf16x8*>(BT + (size_t)(col0 + n * 16 + fr) * K + k0 + fk);
#pragma unroll
    for (int m = 0; m < 4; ++m)
#pragma unroll
      for (int n = 0; n < 4; ++n)
        acc[m][n] = __builtin_amdgcn_mfma_f32_16x16x32_bf16(a[m], b[n], acc[m][n], 0, 0, 0);
  }

  const int cc = lane & 15;
#pragma unroll
  for (int m = 0; m < 4; ++m) {
    float sA = 0.f, sB = 0.f;  // pairs (rows 4q,4q+1) and (4q+2,4q+3)
#pragma unroll
    for (int n = 0; n < 4; ++n) {
      const float bb = bias[col0 + n * 16 + cc];
      const float v0 = acc[m][n][0] + bb;
      const float v1 = acc[m][n][1] + bb;
      const float v2 = acc[m][n][2] + bb;
      const float v3 = acc[m][n][3] + bb;
      sA += v0 * v1;
      sB += v2 * v3;
    }
#pragma unroll
    for (int off = 8; off >= 1; off >>= 1) {
      sA += __shfl_xor(sA, off);
      sB += __shfl_xor(sB, off);
    }
    if (cc == 0) {
      const int p = wr * 32 + m * 8 + 2 * (lane >> 4);
      red[wc][p] = sA;
      red[wc][p + 1] = sB;
    }
  }
  __syncthreads();
  if (threadIdx.x < 64)
    out[blockIdx.x * 64 + threadIdx.x] = red[0][threadIdx.x] + red[1][threadIdx.x];
}

extern "C" void kernel_launch(void* const* d_in, const int* in_sizes, int n_in,
                              void* d_out, int out_size, void* d_ws, size_t ws_size,
                              hipStream_t stream) {
  const float* table = (const float*)d_in[0];
  const int*   pairs = (const int*)d_in[1];
  const float* conc  = (const float*)d_in[2];
  const float* W0    = (const float*)d_in[3];
  const float* b0    = (const float*)d_in[4];
  const float* W1    = (const float*)d_in[5];
  const float* b1    = (const float*)d_in[6];
  const float* W2    = (const float*)d_in[7];
  const float* b2    = (const float*)d_in[8];
  float* out = (float*)d_out;

  // Workspace (16B-aligned, ~111 MB):
  char* ws = (char*)d_ws;
  float*  h0  = (float*)ws;  ws += (size_t)N_DRUGS * D0 * sizeof(float);    // 17.2 MB
  bf16_t* W0b = (bf16_t*)ws; ws += (size_t)N_PROT * D0 * sizeof(bf16_t);    // 38.9 MB
  bf16_t* W1T = (bf16_t*)ws; ws += (size_t)D1 * D0 * sizeof(bf16_t);        //  1.0 MB
  bf16_t* W2T = (bf16_t*)ws; ws += (size_t)D2 * D1 * sizeof(bf16_t);        //  0.13 MB
  bf16_t* H   = (bf16_t*)ws; ws += (size_t)NROWS * D0 * sizeof(bf16_t);     // 33.6 MB
  bf16_t* H1  = (bf16_t*)ws; ws += (size_t)NROWS * D1 * sizeof(bf16_t);     // 16.8 MB
  int* g_idx = (int*)ws;     ws += (size_t)N_DRUGS * MAXNNZ * sizeof(int);  //  3.2 MB
  int* g_cnt = (int*)ws;     ws += (size_t)N_DRUGS * sizeof(int);           // 16.8 KB

  k_convert<<<2048, 256, 0, stream>>>(W0, W1, W2, W0b, W1T, W2T);
  k_scan<<<N_DRUGS, 256, 0, stream>>>((const uint32_t*)table, g_cnt, g_idx);
  k_gather<<<N_DRUGS * NCHUNK, 64, 0, stream>>>(W0b, g_cnt, g_idx, b0, h0);
  k_build_H<<<NROWS, 256, 0, stream>>>(h0, pairs, conc, W0 + (size_t)N_PROT * D0, H);
  k_gemm1<<<dim3(NROWS / 128, D1 / 128), 256, 0, stream>>>(H, W1T, b1, H1);
  k_gemm2_dot<<<NROWS / 128, 256, 0, stream>>>(H1, W2T, b2, out);
}